// Round 10
// baseline (595.838 us; speedup 1.0000x reference)
//
#include <hip/hip_runtime.h>
#include <hip/hip_bf16.h>
#include <hip/hip_fp16.h>
#include <math.h>

#define NN 25000
#define EE 400000
#define BB 64
#define FF 32
#define EDD 8
#define HH 4
#define CC 32
#define HCC 128
#define LL 4
#define LINN 128

#define RSQRT_C 0.17677669529663687f  // 1/sqrt(32)
#define NREP 16                        // bnpart replicas
#define LSTATS_WORDS (NREP * 64)       // bnpart only

// ---------------- CSR build ----------------

__global__ void deg_kernel(const int* __restrict__ dst, int* __restrict__ deg) {
    int i = blockIdx.x * blockDim.x + threadIdx.x;
    if (i < EE) atomicAdd(&deg[dst[i]], 1);
}

// batch_index is sorted: per-graph node offsets via binary search, zero atomics
__global__ void gstart_kernel(const int* __restrict__ bidx, int* __restrict__ gstart) {
    int b = threadIdx.x;
    if (b <= BB) {
        int lo = 0, hi = NN;
        while (lo < hi) { int mid = (lo + hi) >> 1; if (bidx[mid] < b) lo = mid + 1; else hi = mid; }
        gstart[b] = lo;
    }
}

// inclusive scan within 256-blocks; writes to rowp[i+1], block totals to blks
__global__ void scan1_kernel(const int* __restrict__ deg, int* __restrict__ rowp, int* __restrict__ blks) {
    __shared__ int s[256];
    int i = blockIdx.x * 256 + threadIdx.x;
    int v = (i < NN) ? deg[i] : 0;
    s[threadIdx.x] = v;
    __syncthreads();
    for (int off = 1; off < 256; off <<= 1) {
        int t = (threadIdx.x >= off) ? s[threadIdx.x - off] : 0;
        __syncthreads();
        s[threadIdx.x] += t;
        __syncthreads();
    }
    if (i < NN) rowp[i + 1] = s[threadIdx.x];
    if (threadIdx.x == 255) blks[blockIdx.x] = s[255];
    if (i == 0) rowp[0] = 0;
}

// parallel exclusive scan of block totals (nb <= 128)
__global__ void scan2_kernel(int* __restrict__ blks, int nb) {
    __shared__ int s[128];
    int t = threadIdx.x;
    int v = (t < nb) ? blks[t] : 0;
    s[t] = v;
    __syncthreads();
    for (int off = 1; off < 128; off <<= 1) {
        int u = (t >= off) ? s[t - off] : 0;
        __syncthreads();
        s[t] += u;
        __syncthreads();
    }
    if (t < nb) blks[t] = s[t] - v;  // exclusive
}

__global__ void scan3_kernel(int* __restrict__ rowp, const int* __restrict__ blks) {
    int i = blockIdx.x * 256 + threadIdx.x;
    if (i < NN) rowp[i + 1] += blks[blockIdx.x];
}

__global__ void fill_kernel(const int* __restrict__ dst, const int* __restrict__ rowp,
                            int* __restrict__ cnt2, int* __restrict__ eid) {
    int i = blockIdx.x * blockDim.x + threadIdx.x;
    if (i < EE) {
        int d = dst[i];
        int pos = rowp[d] + atomicAdd(&cnt2[d], 1);
        eid[pos] = i;
    }
}

// deterministic order: insertion-sort each node's edge list by edge id (scratch buffer)
__global__ void sortseg_kernel(const int* __restrict__ rowp, int* __restrict__ eid) {
    int n = blockIdx.x * 256 + threadIdx.x;
    if (n >= NN) return;
    int b = rowp[n], e = rowp[n + 1];
    int d = e - b;
    if (d <= 1) return;
    if (d <= 64) {
        int buf[64];
        for (int i = 0; i < d; ++i) buf[i] = eid[b + i];
        for (int i = 1; i < d; ++i) {
            int key = buf[i];
            int j = i - 1;
            while (j >= 0 && buf[j] > key) { buf[j + 1] = buf[j]; --j; }
            buf[j + 1] = key;
        }
        for (int i = 0; i < d; ++i) eid[b + i] = buf[i];
    } else {
        for (int i = b + 1; i < e; ++i) {
            int key = eid[i];
            int j = i - 1;
            while (j >= b && eid[j] > key) { eid[j + 1] = eid[j]; --j; }
            eid[j + 1] = key;
        }
    }
}

// gather src + edge-attr into CSR order (once per call, reused 4 layers)
__global__ void csr_gather_kernel(const int* __restrict__ csre, const int* __restrict__ srcA,
                                  const float* __restrict__ eattr,
                                  int* __restrict__ csrsrc, float4* __restrict__ ecsr) {
    int j = blockIdx.x * blockDim.x + threadIdx.x;
    if (j < EE) {
        int e = csre[j];
        csrsrc[j] = srcA[e];
        const float4* s = (const float4*)(eattr + (size_t)e * 8);
        ecsr[(size_t)j * 2] = s[0];
        ecsr[(size_t)j * 2 + 1] = s[1];
    }
}

// ---------------- per-layer: q,k,v,skip projections ----------------
// wave 0: q, wave 1: k, wave 2: v, wave 3: skip. lane l owns channels 2l, 2l+1.
// All outputs channel-contiguous per node:
//   q, skip: float[128]  (lane writes float2 at node*64+l)
//   k, v:    half[128]   (lane writes half2 at node*64+l)
// block 0 also zeroes the per-layer bnpart region.
__global__ __launch_bounds__(256) void qkvs_kernel(
    const float* __restrict__ hin,
    const float* __restrict__ Wq, const float* __restrict__ bq,
    const float* __restrict__ Wk, const float* __restrict__ bk,
    const float* __restrict__ Wv, const float* __restrict__ bv,
    const float* __restrict__ Ws, const float* __restrict__ bs,
    float2* __restrict__ qo, __half2* __restrict__ ko,
    __half2* __restrict__ vo, float2* __restrict__ so,
    float* __restrict__ lstats)
{
    if (blockIdx.x == 0) {
        for (int i = threadIdx.x; i < LSTATS_WORDS; i += 256) lstats[i] = 0.0f;
    }
    __shared__ float xs[32][32];
    int lane = threadIdx.x & 63;
    int sel = threadIdx.x >> 6;
    const float* W = (sel == 0) ? Wq : (sel == 1) ? Wk : (sel == 2) ? Wv : Ws;
    const float* bias = (sel == 0) ? bq : (sel == 1) ? bk : (sel == 2) ? bv : bs;
    float w0[32], w1[32];
#pragma unroll
    for (int f = 0; f < 32; ++f) {
        float2 t = *(const float2*)&W[f * 128 + 2 * lane];
        w0[f] = t.x; w1[f] = t.y;
    }
    float2 bvv = *(const float2*)&bias[2 * lane];

    for (int chunk = blockIdx.x * 32; chunk < NN; chunk += gridDim.x * 32) {
        __syncthreads();
        for (int i = threadIdx.x; i < 1024; i += 256) {
            int nn = chunk + (i >> 5);
            xs[i >> 5][i & 31] = (nn < NN) ? hin[nn * 32 + (i & 31)] : 0.0f;
        }
        __syncthreads();
        int nmax = NN - chunk; if (nmax > 32) nmax = 32;
        for (int nl = 0; nl < nmax; ++nl) {
            float a0 = bvv.x, a1 = bvv.y;
#pragma unroll
            for (int f = 0; f < 32; ++f) {
                float xv = xs[nl][f];
                a0 += xv * w0[f];
                a1 += xv * w1[f];
            }
            size_t node = (size_t)(chunk + nl);
            if (sel == 0)      qo[node * 64 + lane] = make_float2(a0, a1);
            else if (sel == 1) ko[node * 64 + lane] = __float22half2_rn(make_float2(a0, a1));
            else if (sel == 2) vo[node * 64 + lane] = __float22half2_rn(make_float2(a0, a1));
            else               so[node * 64 + lane] = make_float2(a0, a1);
        }
    }
}

// ---------------- fused attention + beta gate + Wlin + ELU + BN partials ----------------
// 4 waves/block, 1 dst node per wave. Lane: cl=lane&15 owns channels 8cl..8cl+7;
// quarter qt=lane>>4 processes edge j = jb + qt (4 edges per iteration).
// Head = 4 lanes (2-shuffle reduce). kv gathers depth-2 pipelined (8 edges in flight).
// Edge-MLP eliminated algebraically (r[], t[] trick, see r9).
__global__ __launch_bounds__(256) void attn_kernel(
    const float4* __restrict__ qb4, const uint4* __restrict__ kb4,
    const uint4* __restrict__ vb4, const float4* __restrict__ skb4,
    const float4* __restrict__ eb4,       // ecsr (2 float4/slot)
    const int* __restrict__ srcArr,       // csrsrc[j]
    const int* __restrict__ rowp,
    const float* __restrict__ WeL, const float* __restrict__ beL,
    const float* __restrict__ WbL,
    const float* __restrict__ WlinL, const float* __restrict__ blinL,
    float* __restrict__ hlin, float* __restrict__ bnpart)
{
    __shared__ __align__(16) float shc[4 * 128];
    __shared__ float sbn[64];

    int tid = threadIdx.x;
    if (tid < 64) sbn[tid] = 0.0f;
    __syncthreads();

    int w = tid >> 6;
    int lane = tid & 63;
    int n = blockIdx.x * 4 + w;

    if (n < NN) {
        int cl = lane & 15;   // channel group: channels 8cl..8cl+7; head = cl>>2
        int qt = lane >> 4;   // quarter: edge offset within iteration

        const float4* qp = qb4 + (size_t)n * 32 + cl * 2;
        float4 qa = qp[0], qb = qp[1];
        qa.x *= RSQRT_C; qa.y *= RSQRT_C; qa.z *= RSQRT_C; qa.w *= RSQRT_C;
        qb.x *= RSQRT_C; qb.y *= RSQRT_C; qb.z *= RSQRT_C; qb.w *= RSQRT_C;

        // per-node, per-head r[d] = sum_{c in head} We[d,c]*q_c (scaled); qbe = q.be
        float r[8];
        float qbe;
        {
#pragma unroll
            for (int d = 0; d < 8; ++d) {
                float4 wa = *(const float4*)&WeL[d * 128 + 8 * cl];
                float4 wb = *(const float4*)&WeL[d * 128 + 8 * cl + 4];
                r[d] = qa.x * wa.x + qa.y * wa.y + qa.z * wa.z + qa.w * wa.w
                     + qb.x * wb.x + qb.y * wb.y + qb.z * wb.z + qb.w * wb.w;
            }
            float4 bea = *(const float4*)&beL[8 * cl];
            float4 beb = *(const float4*)&beL[8 * cl + 4];
            qbe = qa.x * bea.x + qa.y * bea.y + qa.z * bea.z + qa.w * bea.w
                + qb.x * beb.x + qb.y * beb.y + qb.z * beb.z + qb.w * beb.w;
#pragma unroll
            for (int off = 1; off <= 2; off <<= 1) {
#pragma unroll
                for (int d = 0; d < 8; ++d) r[d] += __shfl_xor(r[d], off);
                qbe += __shfl_xor(qbe, off);
            }
        }

        int beg = rowp[n], end = rowp[n + 1];
        int cnt = end - beg;
        int last = end - 1;

        float s = 0.0f;
        float a0 = 0.f, a1 = 0.f, a2 = 0.f, a3 = 0.f, a4 = 0.f, a5 = 0.f, a6 = 0.f, a7 = 0.f;
        float t0 = 0.f, t1 = 0.f, t2 = 0.f, t3 = 0.f, t4 = 0.f, t5 = 0.f, t6 = 0.f, t7 = 0.f;

        // pipeline: stage A = edge j (consume), stage B = edge j+4 (in flight)
        uint4 kA = make_uint4(0u,0u,0u,0u), vA = kA, kB = kA, vB = kA;
        float4 eaA0 = make_float4(0.f,0.f,0.f,0.f), eaA1 = eaA0, eaB0 = eaA0, eaB1 = eaA0;
        int snC = 0, snD = 0;

        if (cnt > 0) {
            int j0 = beg + qt;      j0 = (j0 < end) ? j0 : last;
            int j1 = beg + 4 + qt;  j1 = (j1 < end) ? j1 : last;
            int j2 = beg + 8 + qt;  j2 = (j2 < end) ? j2 : last;
            int j3 = beg + 12 + qt; j3 = (j3 < end) ? j3 : last;
            int snA = srcArr[j0];
            int snB = srcArr[j1];
            snC = srcArr[j2];
            snD = srcArr[j3];
            kA = kb4[(size_t)snA * 16 + cl];
            vA = vb4[(size_t)snA * 16 + cl];
            kB = kb4[(size_t)snB * 16 + cl];
            vB = vb4[(size_t)snB * 16 + cl];
            eaA0 = eb4[(size_t)j0 * 2];
            eaA1 = eb4[(size_t)j0 * 2 + 1];
            eaB0 = eb4[(size_t)j1 * 2];
            eaB1 = eb4[(size_t)j1 * 2 + 1];
        }

        for (int jb = beg; jb < end; jb += 4) {
            int j = jb + qt;                       // my edge this iteration
            // issue: kv for edge j+8 (2 iters ahead), ea for j+8, src for j+16
            uint4 kC = kb4[(size_t)snC * 16 + cl];
            uint4 vC = vb4[(size_t)snC * 16 + cl];
            int jn = (j + 8 < end) ? j + 8 : last;
            float4 eaC0 = eb4[(size_t)jn * 2];
            float4 eaC1 = eb4[(size_t)jn * 2 + 1];
            int j16 = (j + 16 < end) ? j + 16 : last;
            int snE = srcArr[j16];

            float2 k01 = __half22float2(*(const __half2*)&kA.x);
            float2 k23 = __half22float2(*(const __half2*)&kA.y);
            float2 k45 = __half22float2(*(const __half2*)&kA.z);
            float2 k67 = __half22float2(*(const __half2*)&kA.w);

            // q.k partial over my 8 channels; reduce over 4-lane head group
            float p = qa.x * k01.x + qa.y * k01.y + qa.z * k23.x + qa.w * k23.y
                    + qb.x * k45.x + qb.y * k45.y + qb.z * k67.x + qb.w * k67.y;
            p += __shfl_xor(p, 1);
            p += __shfl_xor(p, 2);
            float pe = eaA0.x * r[0] + eaA0.y * r[1] + eaA0.z * r[2] + eaA0.w * r[3]
                     + eaA1.x * r[4] + eaA1.y * r[5] + eaA1.z * r[6] + eaA1.w * r[7] + qbe;
            float wg = (j < end) ? __expf(p + pe) : 0.0f;
            s += wg;

            float2 v01 = __half22float2(*(const __half2*)&vA.x);
            float2 v23 = __half22float2(*(const __half2*)&vA.y);
            float2 v45 = __half22float2(*(const __half2*)&vA.z);
            float2 v67 = __half22float2(*(const __half2*)&vA.w);
            a0 = fmaf(wg, v01.x, a0);
            a1 = fmaf(wg, v01.y, a1);
            a2 = fmaf(wg, v23.x, a2);
            a3 = fmaf(wg, v23.y, a3);
            a4 = fmaf(wg, v45.x, a4);
            a5 = fmaf(wg, v45.y, a5);
            a6 = fmaf(wg, v67.x, a6);
            a7 = fmaf(wg, v67.y, a7);
            t0 = fmaf(wg, eaA0.x, t0);
            t1 = fmaf(wg, eaA0.y, t1);
            t2 = fmaf(wg, eaA0.z, t2);
            t3 = fmaf(wg, eaA0.w, t3);
            t4 = fmaf(wg, eaA1.x, t4);
            t5 = fmaf(wg, eaA1.y, t5);
            t6 = fmaf(wg, eaA1.z, t6);
            t7 = fmaf(wg, eaA1.w, t7);

            // rotate pipeline
            kA = kB; vA = vB; kB = kC; vB = vC;
            eaA0 = eaB0; eaA1 = eaB1; eaB0 = eaC0; eaB1 = eaC1;
            snC = snD; snD = snE;
        }

        // combine the four quarters (identical channel groups across quarters)
#pragma unroll
        for (int off = 16; off <= 32; off <<= 1) {
            s  += __shfl_xor(s, off);
            a0 += __shfl_xor(a0, off); a1 += __shfl_xor(a1, off);
            a2 += __shfl_xor(a2, off); a3 += __shfl_xor(a3, off);
            a4 += __shfl_xor(a4, off); a5 += __shfl_xor(a5, off);
            a6 += __shfl_xor(a6, off); a7 += __shfl_xor(a7, off);
            t0 += __shfl_xor(t0, off); t1 += __shfl_xor(t1, off);
            t2 += __shfl_xor(t2, off); t3 += __shfl_xor(t3, off);
            t4 += __shfl_xor(t4, off); t5 += __shfl_xor(t5, off);
            t6 += __shfl_xor(t6, off); t7 += __shfl_xor(t7, off);
        }

        // out_c = (A_c + sum_d t_d We[d,c] + s*be_c) / s
        {
            float td[8] = { t0, t1, t2, t3, t4, t5, t6, t7 };
#pragma unroll
            for (int d = 0; d < 8; ++d) {
                float4 wa = *(const float4*)&WeL[d * 128 + 8 * cl];
                float4 wb = *(const float4*)&WeL[d * 128 + 8 * cl + 4];
                a0 = fmaf(td[d], wa.x, a0); a1 = fmaf(td[d], wa.y, a1);
                a2 = fmaf(td[d], wa.z, a2); a3 = fmaf(td[d], wa.w, a3);
                a4 = fmaf(td[d], wb.x, a4); a5 = fmaf(td[d], wb.y, a5);
                a6 = fmaf(td[d], wb.z, a6); a7 = fmaf(td[d], wb.w, a7);
            }
            float4 bea = *(const float4*)&beL[8 * cl];
            float4 beb = *(const float4*)&beL[8 * cl + 4];
            a0 = fmaf(s, bea.x, a0); a1 = fmaf(s, bea.y, a1);
            a2 = fmaf(s, bea.z, a2); a3 = fmaf(s, bea.w, a3);
            a4 = fmaf(s, beb.x, a4); a5 = fmaf(s, beb.y, a5);
            a6 = fmaf(s, beb.z, a6); a7 = fmaf(s, beb.w, a7);
        }

        float rs = (cnt > 0) ? (1.0f / s) : 0.0f;
        float o0 = a0 * rs, o1 = a1 * rs, o2 = a2 * rs, o3 = a3 * rs;
        float o4 = a4 * rs, o5 = a5 * rs, o6 = a6 * rs, o7 = a7 * rs;

        const float4* skp = skb4 + (size_t)n * 32 + cl * 2;
        float4 ska = skp[0], skb_ = skp[1];
        float4 woa = *(const float4*)&WbL[8 * cl];
        float4 wob = *(const float4*)&WbL[8 * cl + 4];
        float4 wsa = *(const float4*)&WbL[128 + 8 * cl];
        float4 wsb = *(const float4*)&WbL[128 + 8 * cl + 4];
        float4 wda = *(const float4*)&WbL[256 + 8 * cl];
        float4 wdb = *(const float4*)&WbL[256 + 8 * cl + 4];

        float tt = o0 * woa.x + ska.x * wsa.x + (o0 - ska.x) * wda.x
                 + o1 * woa.y + ska.y * wsa.y + (o1 - ska.y) * wda.y
                 + o2 * woa.z + ska.z * wsa.z + (o2 - ska.z) * wda.z
                 + o3 * woa.w + ska.w * wsa.w + (o3 - ska.w) * wda.w
                 + o4 * wob.x + skb_.x * wsb.x + (o4 - skb_.x) * wdb.x
                 + o5 * wob.y + skb_.y * wsb.y + (o5 - skb_.y) * wdb.y
                 + o6 * wob.z + skb_.z * wsb.z + (o6 - skb_.z) * wdb.z
                 + o7 * wob.w + skb_.w * wsb.w + (o7 - skb_.w) * wdb.w;
#pragma unroll
        for (int off = 1; off <= 8; off <<= 1) tt += __shfl_xor(tt, off);
        float beta = 1.0f / (1.0f + __expf(-tt));
        float om = 1.0f - beta;
        if (qt == 0) {
            float4 hca, hcb;
            hca.x = beta * ska.x + om * o0;
            hca.y = beta * ska.y + om * o1;
            hca.z = beta * ska.z + om * o2;
            hca.w = beta * ska.w + om * o3;
            hcb.x = beta * skb_.x + om * o4;
            hcb.y = beta * skb_.y + om * o5;
            hcb.z = beta * skb_.z + om * o6;
            hcb.w = beta * skb_.w + om * o7;
            ((float4*)shc)[w * 32 + cl * 2]     = hca;
            ((float4*)shc)[w * 32 + cl * 2 + 1] = hcb;
        }
        // same-wave LDS RAW: no barrier needed
        int cc = lane & 31;
        int half = lane >> 5;
        float acc = 0.0f;
#pragma unroll 8
        for (int i = 0; i < 64; ++i) {
            int ch = half * 64 + i;
            acc += shc[w * 128 + ch] * WlinL[ch * 32 + cc];
        }
        acc += __shfl_xor(acc, 32);
        if (lane < 32) {
            float hv = acc + blinL[lane];
            hv = (hv > 0.0f) ? hv : expm1f(hv);
            hlin[n * 32 + lane] = hv;
            atomicAdd(&sbn[lane], hv);
            atomicAdd(&sbn[32 + lane], hv * hv);
        }
    }
    __syncthreads();
    if (tid < 64) atomicAdd(&bnpart[(blockIdx.x & (NREP - 1)) * 64 + tid], sbn[tid]);
}

// ---------------- BN finalize + normalize + per-graph pool (no atomics) ----------------
// one block per graph; batch_index sorted -> graph g owns nodes [gstart[g], gstart[g+1])
__global__ __launch_bounds__(256) void bnpool_kernel(
    const float* __restrict__ hlin, const float* __restrict__ bnpart,
    const float* __restrict__ gamma, const float* __restrict__ bnbeta,
    const int* __restrict__ gstart,
    float* __restrict__ hc, float* __restrict__ rep, int doPool)
{
    __shared__ float sscale[32], sshift[32];
    __shared__ float smax[8][32], ssum[8][32];
    int tid = threadIdx.x;
    int ch = tid & 31, row = tid >> 5;
    if (tid < 32) {
        float sm = 0.0f, sq = 0.0f;
#pragma unroll
        for (int r = 0; r < NREP; ++r) { sm += bnpart[r * 64 + tid]; sq += bnpart[r * 64 + 32 + tid]; }
        float mean = sm * (1.0f / NN);
        float var = sq * (1.0f / NN) - mean * mean;
        float scale = gamma[tid] * rsqrtf(var + 1e-5f);
        sscale[tid] = scale;
        sshift[tid] = bnbeta[tid] - mean * scale;
    }
    __syncthreads();
    int g = blockIdx.x;
    int gs = gstart[g], ge = gstart[g + 1];
    float scale = sscale[ch], shift = sshift[ch];
    float mx = -1e30f, sum = 0.0f;
    for (int n = gs + row; n < ge; n += 8) {
        float val = hlin[n * 32 + ch] * scale + shift;
        hc[n * 32 + ch] = val;
        mx = fmaxf(mx, val);
        sum += val;
    }
    if (doPool) {
        smax[row][ch] = mx; ssum[row][ch] = sum;
        __syncthreads();
        if (row == 0) {
#pragma unroll
            for (int r = 1; r < 8; ++r) { mx = fmaxf(mx, smax[r][ch]); sum += ssum[r][ch]; }
            int cntg = ge - gs;
            if (cntg > 0) {
                rep[g * 64 + ch]      += mx;
                rep[g * 64 + 32 + ch] += sum / (float)cntg;
            }
        }
    }
}

// ---------------- readout MLP: one block per graph ----------------
__device__ __forceinline__ float eluf(float x) { return x > 0.0f ? x : expm1f(x); }

__global__ __launch_bounds__(128) void readout_kernel(
    const float* __restrict__ rep,
    const float* __restrict__ W1, const float* __restrict__ b1,
    const float* __restrict__ W2, const float* __restrict__ b2,
    const float* __restrict__ W3, const float* __restrict__ b3,
    float* __restrict__ out)
{
    __shared__ float sr[64];
    __shared__ float sz1[128];
    __shared__ float sz2[64];
    int g = blockIdx.x;
    int t = threadIdx.x;
    if (t < 64) sr[t] = rep[g * 64 + t];
    __syncthreads();
    float acc = b1[t];
#pragma unroll 8
    for (int i = 0; i < 64; ++i) acc += sr[i] * W1[i * 128 + t];
    sz1[t] = eluf(acc);
    __syncthreads();
    if (t < 64) {
        float a2 = b2[t];
#pragma unroll 8
        for (int i = 0; i < 128; ++i) a2 += sz1[i] * W2[i * 64 + t];
        sz2[t] = eluf(a2);
    }
    __syncthreads();
    if (t < 64) {
        float p = sz2[t] * W3[t];
#pragma unroll
        for (int off = 1; off <= 32; off <<= 1) p += __shfl_xor(p, off);
        if (t == 0) out[g] = p + b3[0];
    }
}

// ---------------- host ----------------

extern "C" void kernel_launch(void* const* d_in, const int* in_sizes, int n_in,
                              void* d_out, int out_size, void* d_ws, size_t ws_size,
                              hipStream_t stream) {
    const float* x      = (const float*)d_in[0];
    const float* eattr  = (const float*)d_in[1];
    const int*   eidx   = (const int*)d_in[2];
    const int*   bidx   = (const int*)d_in[3];
    const float* Wq     = (const float*)d_in[4];
    const float* bq     = (const float*)d_in[5];
    const float* Wk     = (const float*)d_in[6];
    const float* bk     = (const float*)d_in[7];
    const float* Wv     = (const float*)d_in[8];
    const float* bv     = (const float*)d_in[9];
    const float* We     = (const float*)d_in[10];
    const float* be     = (const float*)d_in[11];
    const float* Wskip  = (const float*)d_in[12];
    const float* bskip  = (const float*)d_in[13];
    const float* Wbeta  = (const float*)d_in[14];
    const float* Wlin   = (const float*)d_in[15];
    const float* blin   = (const float*)d_in[16];
    const float* bng    = (const float*)d_in[17];
    const float* bnb    = (const float*)d_in[18];
    const float* W1     = (const float*)d_in[19];
    const float* b1     = (const float*)d_in[20];
    const float* W2     = (const float*)d_in[21];
    const float* b2     = (const float*)d_in[22];
    const float* W3     = (const float*)d_in[23];
    const float* b3     = (const float*)d_in[24];
    float* out = (float*)d_out;

    char* ws = (char*)d_ws;
    size_t off = 0;
    auto alloc = [&](size_t bytes) -> char* {
        char* p = ws + off;
        off = (off + bytes + 255) & ~(size_t)255;
        return p;
    };
    int*    rowp   = (int*)alloc((NN + 1) * 4);
    int*    degcnt = (int*)alloc(2 * NN * 4);               // deg + cnt2, one memset
    int*    deg    = degcnt;
    int*    cnt2   = degcnt + NN;
    int*    csre   = (int*)alloc(EE * 4);
    int*    blks   = (int*)alloc(128 * 4);
    int*    gstart = (int*)alloc((BB + 1) * 4);
    float*  rep    = (float*)alloc(BB * 64 * 4);
    float4* qB     = (float4*)alloc((size_t)NN * 32 * 16);
    uint4*  kB     = (uint4*)alloc((size_t)NN * 16 * 16);
    uint4*  vB     = (uint4*)alloc((size_t)NN * 16 * 16);
    float4* skB    = (float4*)alloc((size_t)NN * 32 * 16);
    float*  hlin   = (float*)alloc((size_t)NN * 32 * 4);
    float*  hcur   = (float*)alloc((size_t)NN * 32 * 4);
    float*  bnpart = (float*)alloc(LSTATS_WORDS * 4);
    int*    csrsrc = (int*)alloc(EE * 4);
    float4* ecsr   = (float4*)alloc((size_t)EE * 32);

    const int* srcA = eidx;
    const int* dstA = eidx + EE;

    // --- graph prep (once per call) ---
    (void)hipMemsetAsync(degcnt, 0, 2 * NN * 4, stream);
    (void)hipMemsetAsync(rep, 0, BB * 64 * 4, stream);

    deg_kernel<<<(EE + 255) / 256, 256, 0, stream>>>(dstA, deg);
    gstart_kernel<<<1, 128, 0, stream>>>(bidx, gstart);
    scan1_kernel<<<98, 256, 0, stream>>>(deg, rowp, blks);
    scan2_kernel<<<1, 128, 0, stream>>>(blks, 98);
    scan3_kernel<<<98, 256, 0, stream>>>(rowp, blks);
    fill_kernel<<<(EE + 255) / 256, 256, 0, stream>>>(dstA, rowp, cnt2, csre);
    sortseg_kernel<<<98, 256, 0, stream>>>(rowp, csre);
    csr_gather_kernel<<<(EE + 255) / 256, 256, 0, stream>>>(csre, srcA, eattr, csrsrc, ecsr);

    const float* hin = x;
    for (int l = 0; l < LL; ++l) {
        qkvs_kernel<<<782, 256, 0, stream>>>(
            hin,
            Wq + l * FF * HCC, bq + l * HCC,
            Wk + l * FF * HCC, bk + l * HCC,
            Wv + l * FF * HCC, bv + l * HCC,
            Wskip + l * FF * HCC, bskip + l * HCC,
            (float2*)qB, (__half2*)kB, (__half2*)vB, (float2*)skB, bnpart);

        attn_kernel<<<(NN + 3) / 4, 256, 0, stream>>>(
            qB, kB, vB, skB, ecsr, csrsrc, rowp,
            We + l * EDD * HCC, be + l * HCC,
            Wbeta + l * 3 * HCC,
            Wlin + l * HCC * FF, blin + l * FF,
            hlin, bnpart);

        bnpool_kernel<<<BB, 256, 0, stream>>>(hlin, bnpart, bng + l * FF, bnb + l * FF,
                                              gstart, hcur, rep, (l > 0) ? 1 : 0);
        hin = hcur;
    }

    readout_kernel<<<64, 128, 0, stream>>>(rep, W1, b1, W2, b2, W3, b3, out);
}

// Round 11
// 545.293 us; speedup vs baseline: 1.0927x; 1.0927x over previous
//
#include <hip/hip_runtime.h>
#include <hip/hip_bf16.h>
#include <hip/hip_fp16.h>
#include <math.h>

#define NN 25000
#define EE 400000
#define BB 64
#define FF 32
#define EDD 8
#define HH 4
#define CC 32
#define HCC 128
#define LL 4
#define LINN 128

#define RSQRT_C 0.17677669529663687f  // 1/sqrt(32)
#define NREP 16                        // bnpart replicas
#define LSTATS_WORDS (NREP * 64)       // bnpart only

// ---------------- CSR build ----------------

__global__ void deg_kernel(const int* __restrict__ dst, int* __restrict__ deg) {
    int i = blockIdx.x * blockDim.x + threadIdx.x;
    if (i < EE) atomicAdd(&deg[dst[i]], 1);
}

// batch_index is sorted: per-graph node offsets via binary search, zero atomics
__global__ void gstart_kernel(const int* __restrict__ bidx, int* __restrict__ gstart) {
    int b = threadIdx.x;
    if (b <= BB) {
        int lo = 0, hi = NN;
        while (lo < hi) { int mid = (lo + hi) >> 1; if (bidx[mid] < b) lo = mid + 1; else hi = mid; }
        gstart[b] = lo;
    }
}

// inclusive scan within 256-blocks; writes to rowp[i+1], block totals to blks
__global__ void scan1_kernel(const int* __restrict__ deg, int* __restrict__ rowp, int* __restrict__ blks) {
    __shared__ int s[256];
    int i = blockIdx.x * 256 + threadIdx.x;
    int v = (i < NN) ? deg[i] : 0;
    s[threadIdx.x] = v;
    __syncthreads();
    for (int off = 1; off < 256; off <<= 1) {
        int t = (threadIdx.x >= off) ? s[threadIdx.x - off] : 0;
        __syncthreads();
        s[threadIdx.x] += t;
        __syncthreads();
    }
    if (i < NN) rowp[i + 1] = s[threadIdx.x];
    if (threadIdx.x == 255) blks[blockIdx.x] = s[255];
    if (i == 0) rowp[0] = 0;
}

// parallel exclusive scan of block totals (nb <= 128)
__global__ void scan2_kernel(int* __restrict__ blks, int nb) {
    __shared__ int s[128];
    int t = threadIdx.x;
    int v = (t < nb) ? blks[t] : 0;
    s[t] = v;
    __syncthreads();
    for (int off = 1; off < 128; off <<= 1) {
        int u = (t >= off) ? s[t - off] : 0;
        __syncthreads();
        s[t] += u;
        __syncthreads();
    }
    if (t < nb) blks[t] = s[t] - v;  // exclusive
}

__global__ void scan3_kernel(int* __restrict__ rowp, const int* __restrict__ blks) {
    int i = blockIdx.x * 256 + threadIdx.x;
    if (i < NN) rowp[i + 1] += blks[blockIdx.x];
}

__global__ void fill_kernel(const int* __restrict__ dst, const int* __restrict__ rowp,
                            int* __restrict__ cnt2, int* __restrict__ eid) {
    int i = blockIdx.x * blockDim.x + threadIdx.x;
    if (i < EE) {
        int d = dst[i];
        int pos = rowp[d] + atomicAdd(&cnt2[d], 1);
        eid[pos] = i;
    }
}

// deterministic order: insertion-sort each node's edge list by edge id (scratch buffer)
__global__ void sortseg_kernel(const int* __restrict__ rowp, int* __restrict__ eid) {
    int n = blockIdx.x * 256 + threadIdx.x;
    if (n >= NN) return;
    int b = rowp[n], e = rowp[n + 1];
    int d = e - b;
    if (d <= 1) return;
    if (d <= 64) {
        int buf[64];
        for (int i = 0; i < d; ++i) buf[i] = eid[b + i];
        for (int i = 1; i < d; ++i) {
            int key = buf[i];
            int j = i - 1;
            while (j >= 0 && buf[j] > key) { buf[j + 1] = buf[j]; --j; }
            buf[j + 1] = key;
        }
        for (int i = 0; i < d; ++i) eid[b + i] = buf[i];
    } else {
        for (int i = b + 1; i < e; ++i) {
            int key = eid[i];
            int j = i - 1;
            while (j >= b && eid[j] > key) { eid[j + 1] = eid[j]; --j; }
            eid[j + 1] = key;
        }
    }
}

// gather src + edge-attr (fp16-packed) into CSR order (once per call, reused 4 layers)
__global__ void csr_gather_kernel(const int* __restrict__ csre, const int* __restrict__ srcA,
                                  const float* __restrict__ eattr,
                                  int* __restrict__ csrsrc, uint4* __restrict__ eh) {
    int j = blockIdx.x * blockDim.x + threadIdx.x;
    if (j < EE) {
        int e = csre[j];
        csrsrc[j] = srcA[e];
        const float4* s = (const float4*)(eattr + (size_t)e * 8);
        float4 s0 = s[0], s1 = s[1];
        __half2 h0 = __float22half2_rn(make_float2(s0.x, s0.y));
        __half2 h1 = __float22half2_rn(make_float2(s0.z, s0.w));
        __half2 h2 = __float22half2_rn(make_float2(s1.x, s1.y));
        __half2 h3 = __float22half2_rn(make_float2(s1.z, s1.w));
        uint4 o;
        o.x = *(unsigned*)&h0; o.y = *(unsigned*)&h1;
        o.z = *(unsigned*)&h2; o.w = *(unsigned*)&h3;
        eh[j] = o;
    }
}

// ---------------- per-layer: q,k,v,skip projections ----------------
// wave 0: q, wave 1: k, wave 2: v, wave 3: skip. lane l owns channels 2l, 2l+1.
// Layouts (per node, c = 0..31 owning channels 4c..4c+3):
//   q, skip: half[128] channel-contiguous (lane writes half2 slot node*64+l)
//   kv: uint4[32]/node = {h2(k0,k1), h2(k2,k3), h2(v0,v1), h2(v2,v3)} per group c
// block 0 also zeroes the per-layer bnpart region.
__global__ __launch_bounds__(256) void qkvs_kernel(
    const float* __restrict__ hin,
    const float* __restrict__ Wq, const float* __restrict__ bq,
    const float* __restrict__ Wk, const float* __restrict__ bk,
    const float* __restrict__ Wv, const float* __restrict__ bv,
    const float* __restrict__ Ws, const float* __restrict__ bs,
    __half2* __restrict__ qo, __half2* __restrict__ kvo,
    __half2* __restrict__ so, float* __restrict__ lstats)
{
    if (blockIdx.x == 0) {
        for (int i = threadIdx.x; i < LSTATS_WORDS; i += 256) lstats[i] = 0.0f;
    }
    __shared__ float xs[32][32];
    int lane = threadIdx.x & 63;
    int sel = threadIdx.x >> 6;
    const float* W = (sel == 0) ? Wq : (sel == 1) ? Wk : (sel == 2) ? Wv : Ws;
    const float* bias = (sel == 0) ? bq : (sel == 1) ? bk : (sel == 2) ? bv : bs;
    float w0[32], w1[32];
#pragma unroll
    for (int f = 0; f < 32; ++f) {
        float2 t = *(const float2*)&W[f * 128 + 2 * lane];
        w0[f] = t.x; w1[f] = t.y;
    }
    float2 bvv = *(const float2*)&bias[2 * lane];

    int c = lane >> 1;
    int pr = lane & 1;
    int h2k = c * 4 + pr;          // __half2 slot for k within kv row
    int h2v = c * 4 + 2 + pr;      // __half2 slot for v within kv row

    for (int chunk = blockIdx.x * 32; chunk < NN; chunk += gridDim.x * 32) {
        __syncthreads();
        for (int i = threadIdx.x; i < 1024; i += 256) {
            int nn = chunk + (i >> 5);
            xs[i >> 5][i & 31] = (nn < NN) ? hin[nn * 32 + (i & 31)] : 0.0f;
        }
        __syncthreads();
        int nmax = NN - chunk; if (nmax > 32) nmax = 32;
        for (int nl = 0; nl < nmax; ++nl) {
            float a0 = bvv.x, a1 = bvv.y;
#pragma unroll
            for (int f = 0; f < 32; ++f) {
                float xv = xs[nl][f];
                a0 += xv * w0[f];
                a1 += xv * w1[f];
            }
            size_t node = (size_t)(chunk + nl);
            __half2 hv = __float22half2_rn(make_float2(a0, a1));
            if (sel == 0)      qo[node * 64 + lane] = hv;
            else if (sel == 1) kvo[node * 128 + h2k] = hv;
            else if (sel == 2) kvo[node * 128 + h2v] = hv;
            else               so[node * 64 + lane] = hv;
        }
    }
}

// ---------------- fused attention + beta gate + Wlin + ELU + BN partials ----------------
// 4 waves/block, 1 dst node per wave. Lane c=lane&31 owns channels 4c..4c+3;
// half h=lane>>5 processes edge j = jb + h (2 edges per iteration).
// q/sk/ea all fp16 (traffic cut); kv gather depth-2 pipelined.
__global__ __launch_bounds__(256) void attn_kernel(
    const uint2* __restrict__ qh, const uint4* __restrict__ kvb4,
    const uint2* __restrict__ skh,
    const uint4* __restrict__ eh,         // fp16 edge attrs, 16B/edge
    const int* __restrict__ srcArr,       // csrsrc[j]
    const int* __restrict__ rowp,
    const float* __restrict__ WeL, const float* __restrict__ beL,
    const float* __restrict__ WbL,
    const float* __restrict__ WlinL, const float* __restrict__ blinL,
    float* __restrict__ hlin, float* __restrict__ bnpart)
{
    __shared__ __align__(16) float shc[4 * 128];
    __shared__ float sbn[64];

    int tid = threadIdx.x;
    if (tid < 64) sbn[tid] = 0.0f;
    __syncthreads();

    int w = tid >> 6;
    int lane = tid & 63;
    int n = blockIdx.x * 4 + w;

    if (n < NN) {
        int c = lane & 31;
        int h = lane >> 5;

        // per-lane We rows for channels 4c..4c+3
        float4 we[8];
#pragma unroll
        for (int d = 0; d < 8; ++d) we[d] = *(const float4*)&WeL[d * 128 + 4 * c];
        float4 be4 = *(const float4*)&beL[4 * c];

        uint2 qraw = qh[(size_t)n * 32 + c];
        float2 q01 = __half22float2(*(const __half2*)&qraw.x);
        float2 q23 = __half22float2(*(const __half2*)&qraw.y);
        float4 q4 = make_float4(q01.x * RSQRT_C, q01.y * RSQRT_C,
                                q23.x * RSQRT_C, q23.y * RSQRT_C);

        int beg = rowp[n], end = rowp[n + 1];
        int cnt = end - beg;
        int last = end - 1;

        float s = 0.0f, a0 = 0.0f, a1 = 0.0f, a2 = 0.0f, a3 = 0.0f;

        // pipeline state (per half): edges j, j+2 in regs; src for j+4, j+6
        uint4 kvA = make_uint4(0u, 0u, 0u, 0u), kvB = kvA;
        uint4 eaA = kvA, eaB = kvA;
        int snC = 0, snD = 0;

        if (cnt > 0) {
            int j0 = beg + h;     j0 = (j0 < end) ? j0 : last;
            int j1 = beg + 2 + h; j1 = (j1 < end) ? j1 : last;
            int j2 = beg + 4 + h; j2 = (j2 < end) ? j2 : last;
            int j3 = beg + 6 + h; j3 = (j3 < end) ? j3 : last;
            int snA = srcArr[j0];
            int snB = srcArr[j1];
            snC = srcArr[j2];
            snD = srcArr[j3];
            kvA = kvb4[(size_t)snA * 32 + c];
            kvB = kvb4[(size_t)snB * 32 + c];
            eaA = eh[j0];
            eaB = eh[j1];
        }

        for (int jb = beg; jb < end; jb += 2) {
            int j = jb + h;                        // my edge this iteration
            // issue loads: kv for edge j+4 (2 iters ahead), ea for j+4, src for j+8
            uint4 kvC = kvb4[(size_t)snC * 32 + c];
            int jn = (j + 4 < end) ? j + 4 : last;
            uint4 eaC = eh[jn];
            int j8 = (j + 8 < end) ? j + 8 : last;
            int snE = srcArr[j8];

            // unpack edge attrs (8 fp16)
            float2 e01 = __half22float2(*(const __half2*)&eaA.x);
            float2 e23 = __half22float2(*(const __half2*)&eaA.y);
            float2 e45 = __half22float2(*(const __half2*)&eaA.z);
            float2 e67 = __half22float2(*(const __half2*)&eaA.w);
            float ead[8] = { e01.x, e01.y, e23.x, e23.y, e45.x, e45.y, e67.x, e67.y };

            // e-MLP for my 4 channels
            float ex = be4.x, ey = be4.y, ez = be4.z, ew = be4.w;
#pragma unroll
            for (int d = 0; d < 8; ++d) {
                ex = fmaf(ead[d], we[d].x, ex);
                ey = fmaf(ead[d], we[d].y, ey);
                ez = fmaf(ead[d], we[d].z, ez);
                ew = fmaf(ead[d], we[d].w, ew);
            }

            float2 k01 = __half22float2(*(const __half2*)&kvA.x);
            float2 k23 = __half22float2(*(const __half2*)&kvA.y);
            float2 v01 = __half22float2(*(const __half2*)&kvA.z);
            float2 v23 = __half22float2(*(const __half2*)&kvA.w);

            float p = q4.x * (k01.x + ex) + q4.y * (k01.y + ey)
                    + q4.z * (k23.x + ez) + q4.w * (k23.y + ew);
            // head = 8 lanes: 3-shuffle reduce (halves independent)
            p += __shfl_xor(p, 1);
            p += __shfl_xor(p, 2);
            p += __shfl_xor(p, 4);
            float wg = (j < end) ? __expf(p) : 0.0f;
            s += wg;
            a0 = fmaf(wg, v01.x + ex, a0);
            a1 = fmaf(wg, v01.y + ey, a1);
            a2 = fmaf(wg, v23.x + ez, a2);
            a3 = fmaf(wg, v23.y + ew, a3);

            // rotate pipeline
            kvA = kvB; kvB = kvC;
            eaA = eaB; eaB = eaC;
            snC = snD; snD = snE;
        }

        // combine the two halves (bitwise identical both sides)
        s  += __shfl_xor(s, 32);
        a0 += __shfl_xor(a0, 32);
        a1 += __shfl_xor(a1, 32);
        a2 += __shfl_xor(a2, 32);
        a3 += __shfl_xor(a3, 32);

        float rs = (cnt > 0) ? (1.0f / s) : 0.0f;
        float o0 = a0 * rs, o1 = a1 * rs, o2 = a2 * rs, o3 = a3 * rs;

        uint2 skraw = skh[(size_t)n * 32 + c];
        float2 s01 = __half22float2(*(const __half2*)&skraw.x);
        float2 s23 = __half22float2(*(const __half2*)&skraw.y);
        float4 sk4 = make_float4(s01.x, s01.y, s23.x, s23.y);

        float4 wbo = *(const float4*)&WbL[4 * c];
        float4 wbs = *(const float4*)&WbL[128 + 4 * c];
        float4 wbd = *(const float4*)&WbL[256 + 4 * c];

        float t = o0 * wbo.x + sk4.x * wbs.x + (o0 - sk4.x) * wbd.x
                + o1 * wbo.y + sk4.y * wbs.y + (o1 - sk4.y) * wbd.y
                + o2 * wbo.z + sk4.z * wbs.z + (o2 - sk4.z) * wbd.z
                + o3 * wbo.w + sk4.w * wbs.w + (o3 - sk4.w) * wbd.w;
#pragma unroll
        for (int off = 1; off <= 16; off <<= 1) t += __shfl_xor(t, off);
        float beta = 1.0f / (1.0f + __expf(-t));
        float4 hc4;
        hc4.x = beta * sk4.x + (1.0f - beta) * o0;
        hc4.y = beta * sk4.y + (1.0f - beta) * o1;
        hc4.z = beta * sk4.z + (1.0f - beta) * o2;
        hc4.w = beta * sk4.w + (1.0f - beta) * o3;
        if (h == 0) ((float4*)shc)[w * 32 + c] = hc4;
        // same-wave LDS RAW: no barrier needed
        int cc = lane & 31;
        int half = lane >> 5;
        float acc = 0.0f;
#pragma unroll 8
        for (int i = 0; i < 64; ++i) {
            int ch = half * 64 + i;
            acc += shc[w * 128 + ch] * WlinL[ch * 32 + cc];
        }
        acc += __shfl_xor(acc, 32);
        if (lane < 32) {
            float hv = acc + blinL[lane];
            hv = (hv > 0.0f) ? hv : expm1f(hv);
            hlin[n * 32 + lane] = hv;
            atomicAdd(&sbn[lane], hv);
            atomicAdd(&sbn[32 + lane], hv * hv);
        }
    }
    __syncthreads();
    if (tid < 64) atomicAdd(&bnpart[(blockIdx.x & (NREP - 1)) * 64 + tid], sbn[tid]);
}

// ---------------- BN finalize + normalize + per-graph pool (chunked, no atomics) ----------------
// grid = BB*4 blocks: graph g = blockIdx/4, node-chunk = blockIdx%4.
// Partial max/sum per (g,chunk) -> pool4; combined deterministically by pool_combine.
__global__ __launch_bounds__(256) void bnpool_kernel(
    const float* __restrict__ hlin, const float* __restrict__ bnpart,
    const float* __restrict__ gamma, const float* __restrict__ bnbeta,
    const int* __restrict__ gstart,
    float* __restrict__ hc, float* __restrict__ pool4, int doWrite)
{
    __shared__ float sscale[32], sshift[32];
    __shared__ float smax[8][32], ssum[8][32];
    int tid = threadIdx.x;
    int ch = tid & 31, row = tid >> 5;
    if (tid < 32) {
        float sm = 0.0f, sq = 0.0f;
#pragma unroll
        for (int r = 0; r < NREP; ++r) { sm += bnpart[r * 64 + tid]; sq += bnpart[r * 64 + 32 + tid]; }
        float mean = sm * (1.0f / NN);
        float var = sq * (1.0f / NN) - mean * mean;
        float scale = gamma[tid] * rsqrtf(var + 1e-5f);
        sscale[tid] = scale;
        sshift[tid] = bnbeta[tid] - mean * scale;
    }
    __syncthreads();
    int g = blockIdx.x >> 2;
    int chunk = blockIdx.x & 3;
    int gs = gstart[g], ge = gstart[g + 1];
    int len = ge - gs;
    int cs = gs + (len * chunk) / 4;
    int ce = gs + (len * (chunk + 1)) / 4;
    float scale = sscale[ch], shift = sshift[ch];
    float mx = -1e30f, sum = 0.0f;
    for (int n = cs + row; n < ce; n += 8) {
        float val = hlin[n * 32 + ch] * scale + shift;
        if (doWrite) hc[n * 32 + ch] = val;
        mx = fmaxf(mx, val);
        sum += val;
    }
    smax[row][ch] = mx; ssum[row][ch] = sum;
    __syncthreads();
    if (row == 0) {
#pragma unroll
        for (int r = 1; r < 8; ++r) { mx = fmaxf(mx, smax[r][ch]); sum += ssum[r][ch]; }
        pool4[(size_t)blockIdx.x * 64 + ch]      = mx;
        pool4[(size_t)blockIdx.x * 64 + 32 + ch] = sum;
    }
}

// combine 4 chunk-partials into rep (deterministic order)
__global__ void pool_combine_kernel(const float* __restrict__ pool4,
                                    const int* __restrict__ gstart,
                                    float* __restrict__ rep) {
    int i = blockIdx.x * blockDim.x + threadIdx.x;
    if (i < BB * 32) {
        int g = i >> 5, ch = i & 31;
        int cntg = gstart[g + 1] - gstart[g];
        if (cntg > 0) {
            float mx = pool4[(size_t)(g * 4) * 64 + ch];
            float sum = pool4[(size_t)(g * 4) * 64 + 32 + ch];
#pragma unroll
            for (int k = 1; k < 4; ++k) {
                mx = fmaxf(mx, pool4[(size_t)(g * 4 + k) * 64 + ch]);
                sum += pool4[(size_t)(g * 4 + k) * 64 + 32 + ch];
            }
            rep[g * 64 + ch]      += mx;
            rep[g * 64 + 32 + ch] += sum / (float)cntg;
        }
    }
}

// ---------------- readout MLP: one block per graph ----------------
__device__ __forceinline__ float eluf(float x) { return x > 0.0f ? x : expm1f(x); }

__global__ __launch_bounds__(128) void readout_kernel(
    const float* __restrict__ rep,
    const float* __restrict__ W1, const float* __restrict__ b1,
    const float* __restrict__ W2, const float* __restrict__ b2,
    const float* __restrict__ W3, const float* __restrict__ b3,
    float* __restrict__ out)
{
    __shared__ float sr[64];
    __shared__ float sz1[128];
    __shared__ float sz2[64];
    int g = blockIdx.x;
    int t = threadIdx.x;
    if (t < 64) sr[t] = rep[g * 64 + t];
    __syncthreads();
    float acc = b1[t];
#pragma unroll 8
    for (int i = 0; i < 64; ++i) acc += sr[i] * W1[i * 128 + t];
    sz1[t] = eluf(acc);
    __syncthreads();
    if (t < 64) {
        float a2 = b2[t];
#pragma unroll 8
        for (int i = 0; i < 128; ++i) a2 += sz1[i] * W2[i * 64 + t];
        sz2[t] = eluf(a2);
    }
    __syncthreads();
    if (t < 64) {
        float p = sz2[t] * W3[t];
#pragma unroll
        for (int off = 1; off <= 32; off <<= 1) p += __shfl_xor(p, off);
        if (t == 0) out[g] = p + b3[0];
    }
}

// ---------------- host ----------------

extern "C" void kernel_launch(void* const* d_in, const int* in_sizes, int n_in,
                              void* d_out, int out_size, void* d_ws, size_t ws_size,
                              hipStream_t stream) {
    const float* x      = (const float*)d_in[0];
    const float* eattr  = (const float*)d_in[1];
    const int*   eidx   = (const int*)d_in[2];
    const int*   bidx   = (const int*)d_in[3];
    const float* Wq     = (const float*)d_in[4];
    const float* bq     = (const float*)d_in[5];
    const float* Wk     = (const float*)d_in[6];
    const float* bk     = (const float*)d_in[7];
    const float* Wv     = (const float*)d_in[8];
    const float* bv     = (const float*)d_in[9];
    const float* We     = (const float*)d_in[10];
    const float* be     = (const float*)d_in[11];
    const float* Wskip  = (const float*)d_in[12];
    const float* bskip  = (const float*)d_in[13];
    const float* Wbeta  = (const float*)d_in[14];
    const float* Wlin   = (const float*)d_in[15];
    const float* blin   = (const float*)d_in[16];
    const float* bng    = (const float*)d_in[17];
    const float* bnb    = (const float*)d_in[18];
    const float* W1     = (const float*)d_in[19];
    const float* b1     = (const float*)d_in[20];
    const float* W2     = (const float*)d_in[21];
    const float* b2     = (const float*)d_in[22];
    const float* W3     = (const float*)d_in[23];
    const float* b3     = (const float*)d_in[24];
    float* out = (float*)d_out;

    char* ws = (char*)d_ws;
    size_t off = 0;
    auto alloc = [&](size_t bytes) -> char* {
        char* p = ws + off;
        off = (off + bytes + 255) & ~(size_t)255;
        return p;
    };
    int*     rowp   = (int*)alloc((NN + 1) * 4);
    int*     degcnt = (int*)alloc(2 * NN * 4);              // deg + cnt2, one memset
    int*     deg    = degcnt;
    int*     cnt2   = degcnt + NN;
    int*     csre   = (int*)alloc(EE * 4);
    int*     blks   = (int*)alloc(128 * 4);
    int*     gstart = (int*)alloc((BB + 1) * 4);
    float*   rep    = (float*)alloc(BB * 64 * 4);
    float*   pool4  = (float*)alloc(BB * 4 * 64 * 4);
    __half2* qH     = (__half2*)alloc((size_t)NN * 64 * 4);   // fp16 q
    __half2* kvB    = (__half2*)alloc((size_t)NN * 128 * 4);  // fp16 kv interleaved
    __half2* skH    = (__half2*)alloc((size_t)NN * 64 * 4);   // fp16 skip
    float*   hlin   = (float*)alloc((size_t)NN * 32 * 4);
    float*   hcur   = (float*)alloc((size_t)NN * 32 * 4);
    float*   bnpart = (float*)alloc(LSTATS_WORDS * 4);
    int*     csrsrc = (int*)alloc(EE * 4);
    uint4*   ecsrh  = (uint4*)alloc((size_t)EE * 16);         // fp16 edge attrs

    const int* srcA = eidx;
    const int* dstA = eidx + EE;

    // --- graph prep (once per call) ---
    (void)hipMemsetAsync(degcnt, 0, 2 * NN * 4, stream);
    (void)hipMemsetAsync(rep, 0, BB * 64 * 4, stream);

    deg_kernel<<<(EE + 255) / 256, 256, 0, stream>>>(dstA, deg);
    gstart_kernel<<<1, 128, 0, stream>>>(bidx, gstart);
    scan1_kernel<<<98, 256, 0, stream>>>(deg, rowp, blks);
    scan2_kernel<<<1, 128, 0, stream>>>(blks, 98);
    scan3_kernel<<<98, 256, 0, stream>>>(rowp, blks);
    fill_kernel<<<(EE + 255) / 256, 256, 0, stream>>>(dstA, rowp, cnt2, csre);
    sortseg_kernel<<<98, 256, 0, stream>>>(rowp, csre);
    csr_gather_kernel<<<(EE + 255) / 256, 256, 0, stream>>>(csre, srcA, eattr, csrsrc, ecsrh);

    const float* hin = x;
    for (int l = 0; l < LL; ++l) {
        qkvs_kernel<<<782, 256, 0, stream>>>(
            hin,
            Wq + l * FF * HCC, bq + l * HCC,
            Wk + l * FF * HCC, bk + l * HCC,
            Wv + l * FF * HCC, bv + l * HCC,
            Wskip + l * FF * HCC, bskip + l * HCC,
            qH, kvB, skH, bnpart);

        attn_kernel<<<(NN + 3) / 4, 256, 0, stream>>>(
            (const uint2*)qH, (const uint4*)kvB, (const uint2*)skH,
            ecsrh, csrsrc, rowp,
            We + l * EDD * HCC, be + l * HCC,
            Wbeta + l * 3 * HCC,
            Wlin + l * HCC * FF, blin + l * FF,
            hlin, bnpart);

        bnpool_kernel<<<BB * 4, 256, 0, stream>>>(hlin, bnpart, bng + l * FF, bnb + l * FF,
                                                  gstart, hcur, pool4, (l < LL - 1) ? 1 : 0);
        if (l > 0) {
            pool_combine_kernel<<<8, 256, 0, stream>>>(pool4, gstart, rep);
        }
        hin = hcur;
    }

    readout_kernel<<<64, 128, 0, stream>>>(rep, W1, b1, W2, b2, W3, b3, out);
}

// Round 12
// 541.240 us; speedup vs baseline: 1.1009x; 1.0075x over previous
//
#include <hip/hip_runtime.h>
#include <hip/hip_bf16.h>
#include <hip/hip_fp16.h>
#include <math.h>

#define NN 25000
#define EE 400000
#define BB 64
#define FF 32
#define EDD 8
#define HH 4
#define CC 32
#define HCC 128
#define LL 4
#define LINN 128

#define RSQRT_C 0.17677669529663687f  // 1/sqrt(32)
#define NREP 16                        // bnpart replicas
#define NREPP 8                        // pool replicas
// lstats layout: bnpart[NREP*64] | gmax[NREPP*BB*32] (uint) | gsum[NREPP*BB*32]
#define GMAX_OFF (NREP * 64)
#define GSUM_OFF (NREP * 64 + NREPP * BB * 32)
#define LSTATS_WORDS (NREP * 64 + 2 * NREPP * BB * 32)

// ---------------- CSR build ----------------

__global__ void deg_kernel(const int* __restrict__ dst, int* __restrict__ deg) {
    int i = blockIdx.x * blockDim.x + threadIdx.x;
    if (i < EE) atomicAdd(&deg[dst[i]], 1);
}

// inclusive scan within 256-blocks; writes to rowp[i+1], block totals to blks
__global__ void scan1_kernel(const int* __restrict__ deg, int* __restrict__ rowp, int* __restrict__ blks) {
    __shared__ int s[256];
    int i = blockIdx.x * 256 + threadIdx.x;
    int v = (i < NN) ? deg[i] : 0;
    s[threadIdx.x] = v;
    __syncthreads();
    for (int off = 1; off < 256; off <<= 1) {
        int t = (threadIdx.x >= off) ? s[threadIdx.x - off] : 0;
        __syncthreads();
        s[threadIdx.x] += t;
        __syncthreads();
    }
    if (i < NN) rowp[i + 1] = s[threadIdx.x];
    if (threadIdx.x == 255) blks[blockIdx.x] = s[255];
    if (i == 0) rowp[0] = 0;
}

// parallel exclusive scan of block totals (nb <= 128) + gstart binary searches
__global__ void scan2_kernel(int* __restrict__ blks, int nb,
                             const int* __restrict__ bidx, int* __restrict__ gstart) {
    __shared__ int s[128];
    int t = threadIdx.x;
    int v = (t < nb) ? blks[t] : 0;
    s[t] = v;
    __syncthreads();
    for (int off = 1; off < 128; off <<= 1) {
        int u = (t >= off) ? s[t - off] : 0;
        __syncthreads();
        s[t] += u;
        __syncthreads();
    }
    if (t < nb) blks[t] = s[t] - v;  // exclusive
    if (t <= BB) {
        int lo = 0, hi = NN;
        while (lo < hi) { int mid = (lo + hi) >> 1; if (bidx[mid] < t) lo = mid + 1; else hi = mid; }
        gstart[t] = lo;
    }
}

__global__ void scan3_kernel(int* __restrict__ rowp, const int* __restrict__ blks) {
    int i = blockIdx.x * 256 + threadIdx.x;
    if (i < NN) rowp[i + 1] += blks[blockIdx.x];
}

__global__ void fill_kernel(const int* __restrict__ dst, const int* __restrict__ rowp,
                            int* __restrict__ cnt2, int* __restrict__ eid) {
    int i = blockIdx.x * blockDim.x + threadIdx.x;
    if (i < EE) {
        int d = dst[i];
        int pos = rowp[d] + atomicAdd(&cnt2[d], 1);
        eid[pos] = i;
    }
}

// deterministic order: insertion-sort each node's edge list by edge id (scratch buffer)
__global__ void sortseg_kernel(const int* __restrict__ rowp, int* __restrict__ eid) {
    int n = blockIdx.x * 256 + threadIdx.x;
    if (n >= NN) return;
    int b = rowp[n], e = rowp[n + 1];
    int d = e - b;
    if (d <= 1) return;
    if (d <= 64) {
        int buf[64];
        for (int i = 0; i < d; ++i) buf[i] = eid[b + i];
        for (int i = 1; i < d; ++i) {
            int key = buf[i];
            int j = i - 1;
            while (j >= 0 && buf[j] > key) { buf[j + 1] = buf[j]; --j; }
            buf[j + 1] = key;
        }
        for (int i = 0; i < d; ++i) eid[b + i] = buf[i];
    } else {
        for (int i = b + 1; i < e; ++i) {
            int key = eid[i];
            int j = i - 1;
            while (j >= b && eid[j] > key) { eid[j + 1] = eid[j]; --j; }
            eid[j + 1] = key;
        }
    }
}

// gather src + edge-attr (fp16-packed) into CSR order (once per call, reused 4 layers)
__global__ void csr_gather_kernel(const int* __restrict__ csre, const int* __restrict__ srcA,
                                  const float* __restrict__ eattr,
                                  int* __restrict__ csrsrc, uint4* __restrict__ eh) {
    int j = blockIdx.x * blockDim.x + threadIdx.x;
    if (j < EE) {
        int e = csre[j];
        csrsrc[j] = srcA[e];
        const float4* s = (const float4*)(eattr + (size_t)e * 8);
        float4 s0 = s[0], s1 = s[1];
        __half2 h0 = __float22half2_rn(make_float2(s0.x, s0.y));
        __half2 h1 = __float22half2_rn(make_float2(s0.z, s0.w));
        __half2 h2 = __float22half2_rn(make_float2(s1.x, s1.y));
        __half2 h3 = __float22half2_rn(make_float2(s1.z, s1.w));
        uint4 o;
        o.x = *(unsigned*)&h0; o.y = *(unsigned*)&h1;
        o.z = *(unsigned*)&h2; o.w = *(unsigned*)&h3;
        eh[j] = o;
    }
}

// ---------------- per-layer: q,k,v,skip projections (+inline BN of input) ----------------
// wave 0: q, wave 1: k, wave 2: v, wave 3: skip. lane l owns channels 2l, 2l+1.
// Input: hin fp32 [N,32]; if applyBN, val = val*bnss[ch] + bnss[32+ch] on load.
// block 0 also zeroes the per-layer stats region (bnpart + gmax + gsum).
__global__ __launch_bounds__(256) void qkvs_kernel(
    const float* __restrict__ hin, int applyBN, const float* __restrict__ bnss,
    const float* __restrict__ Wq, const float* __restrict__ bq,
    const float* __restrict__ Wk, const float* __restrict__ bk,
    const float* __restrict__ Wv, const float* __restrict__ bv,
    const float* __restrict__ Ws, const float* __restrict__ bs,
    __half2* __restrict__ qo, __half2* __restrict__ kvo,
    __half2* __restrict__ so, float* __restrict__ lstats)
{
    if (blockIdx.x == 0) {
        for (int i = threadIdx.x; i < LSTATS_WORDS; i += 256) lstats[i] = 0.0f;
    }
    __shared__ float xs[32][32];
    __shared__ float sbns[64];
    if (threadIdx.x < 64) sbns[threadIdx.x] = applyBN ? bnss[threadIdx.x] : (threadIdx.x < 32 ? 1.0f : 0.0f);
    int lane = threadIdx.x & 63;
    int sel = threadIdx.x >> 6;
    const float* W = (sel == 0) ? Wq : (sel == 1) ? Wk : (sel == 2) ? Wv : Ws;
    const float* bias = (sel == 0) ? bq : (sel == 1) ? bk : (sel == 2) ? bv : bs;
    float w0[32], w1[32];
#pragma unroll
    for (int f = 0; f < 32; ++f) {
        float2 t = *(const float2*)&W[f * 128 + 2 * lane];
        w0[f] = t.x; w1[f] = t.y;
    }
    float2 bvv = *(const float2*)&bias[2 * lane];

    int c = lane >> 1;
    int pr = lane & 1;
    int h2k = c * 4 + pr;          // __half2 slot for k within kv row
    int h2v = c * 4 + 2 + pr;      // __half2 slot for v within kv row

    for (int chunk = blockIdx.x * 32; chunk < NN; chunk += gridDim.x * 32) {
        __syncthreads();
        for (int i = threadIdx.x; i < 1024; i += 256) {
            int nn = chunk + (i >> 5);
            int ch = i & 31;
            float v = (nn < NN) ? hin[nn * 32 + ch] : 0.0f;
            xs[i >> 5][ch] = v * sbns[ch] + sbns[32 + ch];
        }
        __syncthreads();
        int nmax = NN - chunk; if (nmax > 32) nmax = 32;
        for (int nl = 0; nl < nmax; ++nl) {
            float a0 = bvv.x, a1 = bvv.y;
#pragma unroll
            for (int f = 0; f < 32; ++f) {
                float xv = xs[nl][f];
                a0 += xv * w0[f];
                a1 += xv * w1[f];
            }
            size_t node = (size_t)(chunk + nl);
            __half2 hv = __float22half2_rn(make_float2(a0, a1));
            if (sel == 0)      qo[node * 64 + lane] = hv;
            else if (sel == 1) kvo[node * 128 + h2k] = hv;
            else if (sel == 2) kvo[node * 128 + h2v] = hv;
            else               so[node * 64 + lane] = hv;
        }
    }
}

__device__ __forceinline__ unsigned fmap_u(float x) {
    unsigned u = __float_as_uint(x);
    return (u & 0x80000000u) ? ~u : (u | 0x80000000u);
}
__device__ __forceinline__ float funmap_u(unsigned u) {
    unsigned b = (u & 0x80000000u) ? (u & 0x7fffffffu) : ~u;
    return __uint_as_float(b);
}

// ---------------- fused attention + beta gate + Wlin + ELU + BN partials + pool partials ----------------
// 4 waves/block, 1 dst node per wave. Lane c=lane&31 owns channels 4c..4c+3;
// half h=lane>>5 processes edge j = jb + h (2 edges per iteration).
__global__ __launch_bounds__(256) void attn_kernel(
    const uint2* __restrict__ qh, const uint4* __restrict__ kvb4,
    const uint2* __restrict__ skh,
    const uint4* __restrict__ eh,         // fp16 edge attrs, 16B/edge
    const int* __restrict__ srcArr,       // csrsrc[j]
    const int* __restrict__ rowp,
    const int* __restrict__ bidx,
    const float* __restrict__ WeL, const float* __restrict__ beL,
    const float* __restrict__ WbL,
    const float* __restrict__ WlinL, const float* __restrict__ blinL,
    float* __restrict__ hlin, float* __restrict__ lstats,
    int doPool, int doWriteH)
{
    __shared__ __align__(16) float shc[4 * 128];
    __shared__ float sbn[64];

    int tid = threadIdx.x;
    if (tid < 64) sbn[tid] = 0.0f;
    __syncthreads();

    int w = tid >> 6;
    int lane = tid & 63;
    int n = blockIdx.x * 4 + w;

    if (n < NN) {
        int c = lane & 31;
        int h = lane >> 5;

        // per-lane We rows for channels 4c..4c+3
        float4 we[8];
#pragma unroll
        for (int d = 0; d < 8; ++d) we[d] = *(const float4*)&WeL[d * 128 + 4 * c];
        float4 be4 = *(const float4*)&beL[4 * c];

        uint2 qraw = qh[(size_t)n * 32 + c];
        float2 q01 = __half22float2(*(const __half2*)&qraw.x);
        float2 q23 = __half22float2(*(const __half2*)&qraw.y);
        float4 q4 = make_float4(q01.x * RSQRT_C, q01.y * RSQRT_C,
                                q23.x * RSQRT_C, q23.y * RSQRT_C);

        int beg = rowp[n], end = rowp[n + 1];
        int cnt = end - beg;
        int last = end - 1;

        float s = 0.0f, a0 = 0.0f, a1 = 0.0f, a2 = 0.0f, a3 = 0.0f;

        // pipeline state (per half): edges j, j+2 in regs; src for j+4, j+6
        uint4 kvA = make_uint4(0u, 0u, 0u, 0u), kvB = kvA;
        uint4 eaA = kvA, eaB = kvA;
        int snC = 0, snD = 0;

        if (cnt > 0) {
            int j0 = beg + h;     j0 = (j0 < end) ? j0 : last;
            int j1 = beg + 2 + h; j1 = (j1 < end) ? j1 : last;
            int j2 = beg + 4 + h; j2 = (j2 < end) ? j2 : last;
            int j3 = beg + 6 + h; j3 = (j3 < end) ? j3 : last;
            int snA = srcArr[j0];
            int snB = srcArr[j1];
            snC = srcArr[j2];
            snD = srcArr[j3];
            kvA = kvb4[(size_t)snA * 32 + c];
            kvB = kvb4[(size_t)snB * 32 + c];
            eaA = eh[j0];
            eaB = eh[j1];
        }

        for (int jb = beg; jb < end; jb += 2) {
            int j = jb + h;                        // my edge this iteration
            // issue loads: kv for edge j+4 (2 iters ahead), ea for j+4, src for j+8
            uint4 kvC = kvb4[(size_t)snC * 32 + c];
            int jn = (j + 4 < end) ? j + 4 : last;
            uint4 eaC = eh[jn];
            int j8 = (j + 8 < end) ? j + 8 : last;
            int snE = srcArr[j8];

            // unpack edge attrs (8 fp16)
            float2 e01 = __half22float2(*(const __half2*)&eaA.x);
            float2 e23 = __half22float2(*(const __half2*)&eaA.y);
            float2 e45 = __half22float2(*(const __half2*)&eaA.z);
            float2 e67 = __half22float2(*(const __half2*)&eaA.w);
            float ead[8] = { e01.x, e01.y, e23.x, e23.y, e45.x, e45.y, e67.x, e67.y };

            // e-MLP for my 4 channels
            float ex = be4.x, ey = be4.y, ez = be4.z, ew = be4.w;
#pragma unroll
            for (int d = 0; d < 8; ++d) {
                ex = fmaf(ead[d], we[d].x, ex);
                ey = fmaf(ead[d], we[d].y, ey);
                ez = fmaf(ead[d], we[d].z, ez);
                ew = fmaf(ead[d], we[d].w, ew);
            }

            float2 k01 = __half22float2(*(const __half2*)&kvA.x);
            float2 k23 = __half22float2(*(const __half2*)&kvA.y);
            float2 v01 = __half22float2(*(const __half2*)&kvA.z);
            float2 v23 = __half22float2(*(const __half2*)&kvA.w);

            float p = q4.x * (k01.x + ex) + q4.y * (k01.y + ey)
                    + q4.z * (k23.x + ez) + q4.w * (k23.y + ew);
            // head = 8 lanes: 3-shuffle reduce (halves independent)
            p += __shfl_xor(p, 1);
            p += __shfl_xor(p, 2);
            p += __shfl_xor(p, 4);
            float wg = (j < end) ? __expf(p) : 0.0f;
            s += wg;
            a0 = fmaf(wg, v01.x + ex, a0);
            a1 = fmaf(wg, v01.y + ey, a1);
            a2 = fmaf(wg, v23.x + ez, a2);
            a3 = fmaf(wg, v23.y + ew, a3);

            // rotate pipeline
            kvA = kvB; kvB = kvC;
            eaA = eaB; eaB = eaC;
            snC = snD; snD = snE;
        }

        // combine the two halves (bitwise identical both sides)
        s  += __shfl_xor(s, 32);
        a0 += __shfl_xor(a0, 32);
        a1 += __shfl_xor(a1, 32);
        a2 += __shfl_xor(a2, 32);
        a3 += __shfl_xor(a3, 32);

        float rs = (cnt > 0) ? (1.0f / s) : 0.0f;
        float o0 = a0 * rs, o1 = a1 * rs, o2 = a2 * rs, o3 = a3 * rs;

        uint2 skraw = skh[(size_t)n * 32 + c];
        float2 s01 = __half22float2(*(const __half2*)&skraw.x);
        float2 s23 = __half22float2(*(const __half2*)&skraw.y);
        float4 sk4 = make_float4(s01.x, s01.y, s23.x, s23.y);

        float4 wbo = *(const float4*)&WbL[4 * c];
        float4 wbs = *(const float4*)&WbL[128 + 4 * c];
        float4 wbd = *(const float4*)&WbL[256 + 4 * c];

        float t = o0 * wbo.x + sk4.x * wbs.x + (o0 - sk4.x) * wbd.x
                + o1 * wbo.y + sk4.y * wbs.y + (o1 - sk4.y) * wbd.y
                + o2 * wbo.z + sk4.z * wbs.z + (o2 - sk4.z) * wbd.z
                + o3 * wbo.w + sk4.w * wbs.w + (o3 - sk4.w) * wbd.w;
#pragma unroll
        for (int off = 1; off <= 16; off <<= 1) t += __shfl_xor(t, off);
        float beta = 1.0f / (1.0f + __expf(-t));
        float4 hc4;
        hc4.x = beta * sk4.x + (1.0f - beta) * o0;
        hc4.y = beta * sk4.y + (1.0f - beta) * o1;
        hc4.z = beta * sk4.z + (1.0f - beta) * o2;
        hc4.w = beta * sk4.w + (1.0f - beta) * o3;
        if (h == 0) ((float4*)shc)[w * 32 + c] = hc4;
        // same-wave LDS RAW: no barrier needed
        int cc = lane & 31;
        int half = lane >> 5;
        float acc = 0.0f;
#pragma unroll 8
        for (int i = 0; i < 64; ++i) {
            int ch = half * 64 + i;
            acc += shc[w * 128 + ch] * WlinL[ch * 32 + cc];
        }
        acc += __shfl_xor(acc, 32);
        if (lane < 32) {
            float hv = acc + blinL[lane];
            hv = (hv > 0.0f) ? hv : expm1f(hv);
            if (doWriteH) hlin[n * 32 + lane] = hv;
            atomicAdd(&sbn[lane], hv);
            atomicAdd(&sbn[32 + lane], hv * hv);
            if (doPool) {
                int g = bidx[n];
                int repv = blockIdx.x & (NREPP - 1);
                size_t idx = ((size_t)repv * BB + g) * 32 + lane;
                atomicMax((unsigned*)lstats + GMAX_OFF + idx, fmap_u(hv));
                atomicAdd(lstats + GSUM_OFF + idx, hv);
            }
        }
    }
    __syncthreads();
    if (tid < 64) atomicAdd(&lstats[(blockIdx.x & (NREP - 1)) * 64 + tid], sbn[tid]);
}

// ---------------- BN finalize: bnss = {scale[32], shift[32]} ----------------
__global__ void bnfin_kernel(const float* __restrict__ bnpart,
                             const float* __restrict__ gamma, const float* __restrict__ bnbeta,
                             float* __restrict__ bnss) {
    int c = threadIdx.x;
    if (c < 32) {
        float sm = 0.0f, sq = 0.0f;
#pragma unroll
        for (int r = 0; r < NREP; ++r) { sm += bnpart[r * 64 + c]; sq += bnpart[r * 64 + 32 + c]; }
        float mean = sm * (1.0f / NN);
        float var = sq * (1.0f / NN) - mean * mean;
        float scale = gamma[c] * rsqrtf(var + 1e-5f);
        bnss[c] = scale;
        bnss[32 + c] = bnbeta[c] - mean * scale;
    }
}

// ---------------- rep update from pool partials (scale>0: affine transform of pre-BN stats) ----------------
__global__ void repupd_kernel(const float* __restrict__ lstats, const float* __restrict__ bnss,
                              const int* __restrict__ gstart, float* __restrict__ rep, int assign) {
    int i = blockIdx.x * blockDim.x + threadIdx.x;
    if (i < BB * 32) {
        int g = i >> 5, ch = i & 31;
        int cntg = gstart[g + 1] - gstart[g];
        float vmax = 0.0f, vmean = 0.0f;
        if (cntg > 0) {
            const unsigned* gm = (const unsigned*)lstats + GMAX_OFF;
            const float* gs = lstats + GSUM_OFF;
            unsigned mx = 0u;
            float sum = 0.0f;
#pragma unroll
            for (int r = 0; r < NREPP; ++r) {
                size_t idx = ((size_t)r * BB + g) * 32 + ch;
                unsigned m = gm[idx];
                mx = (m > mx) ? m : mx;
                sum += gs[idx];
            }
            float scale = bnss[ch], shift = bnss[32 + ch];
            vmax = scale * funmap_u(mx) + shift;
            vmean = scale * (sum / (float)cntg) + shift;
        }
        if (assign) {
            rep[g * 64 + ch] = vmax;
            rep[g * 64 + 32 + ch] = vmean;
        } else {
            rep[g * 64 + ch] += vmax;
            rep[g * 64 + 32 + ch] += vmean;
        }
    }
}

// ---------------- readout MLP: one block per graph ----------------
__device__ __forceinline__ float eluf(float x) { return x > 0.0f ? x : expm1f(x); }

__global__ __launch_bounds__(128) void readout_kernel(
    const float* __restrict__ rep,
    const float* __restrict__ W1, const float* __restrict__ b1,
    const float* __restrict__ W2, const float* __restrict__ b2,
    const float* __restrict__ W3, const float* __restrict__ b3,
    float* __restrict__ out)
{
    __shared__ float sr[64];
    __shared__ float sz1[128];
    __shared__ float sz2[64];
    int g = blockIdx.x;
    int t = threadIdx.x;
    if (t < 64) sr[t] = rep[g * 64 + t];
    __syncthreads();
    float acc = b1[t];
#pragma unroll 8
    for (int i = 0; i < 64; ++i) acc += sr[i] * W1[i * 128 + t];
    sz1[t] = eluf(acc);
    __syncthreads();
    if (t < 64) {
        float a2 = b2[t];
#pragma unroll 8
        for (int i = 0; i < 128; ++i) a2 += sz1[i] * W2[i * 64 + t];
        sz2[t] = eluf(a2);
    }
    __syncthreads();
    if (t < 64) {
        float p = sz2[t] * W3[t];
#pragma unroll
        for (int off = 1; off <= 32; off <<= 1) p += __shfl_xor(p, off);
        if (t == 0) out[g] = p + b3[0];
    }
}

// ---------------- host ----------------

extern "C" void kernel_launch(void* const* d_in, const int* in_sizes, int n_in,
                              void* d_out, int out_size, void* d_ws, size_t ws_size,
                              hipStream_t stream) {
    const float* x      = (const float*)d_in[0];
    const float* eattr  = (const float*)d_in[1];
    const int*   eidx   = (const int*)d_in[2];
    const int*   bidx   = (const int*)d_in[3];
    const float* Wq     = (const float*)d_in[4];
    const float* bq     = (const float*)d_in[5];
    const float* Wk     = (const float*)d_in[6];
    const float* bk     = (const float*)d_in[7];
    const float* Wv     = (const float*)d_in[8];
    const float* bv     = (const float*)d_in[9];
    const float* We     = (const float*)d_in[10];
    const float* be     = (const float*)d_in[11];
    const float* Wskip  = (const float*)d_in[12];
    const float* bskip  = (const float*)d_in[13];
    const float* Wbeta  = (const float*)d_in[14];
    const float* Wlin   = (const float*)d_in[15];
    const float* blin   = (const float*)d_in[16];
    const float* bng    = (const float*)d_in[17];
    const float* bnb    = (const float*)d_in[18];
    const float* W1     = (const float*)d_in[19];
    const float* b1     = (const float*)d_in[20];
    const float* W2     = (const float*)d_in[21];
    const float* b2     = (const float*)d_in[22];
    const float* W3     = (const float*)d_in[23];
    const float* b3     = (const float*)d_in[24];
    float* out = (float*)d_out;

    char* ws = (char*)d_ws;
    size_t off = 0;
    auto alloc = [&](size_t bytes) -> char* {
        char* p = ws + off;
        off = (off + bytes + 255) & ~(size_t)255;
        return p;
    };
    int*     rowp   = (int*)alloc((NN + 1) * 4);
    int*     degcnt = (int*)alloc(2 * NN * 4);              // deg + cnt2, one memset
    int*     deg    = degcnt;
    int*     cnt2   = degcnt + NN;
    int*     csre   = (int*)alloc(EE * 4);
    int*     blks   = (int*)alloc(128 * 4);
    int*     gstart = (int*)alloc((BB + 1) * 4);
    float*   rep    = (float*)alloc(BB * 64 * 4);
    __half2* qH     = (__half2*)alloc((size_t)NN * 64 * 4);   // fp16 q
    __half2* kvB    = (__half2*)alloc((size_t)NN * 128 * 4);  // fp16 kv interleaved
    __half2* skH    = (__half2*)alloc((size_t)NN * 64 * 4);   // fp16 skip
    float*   hlin   = (float*)alloc((size_t)NN * 32 * 4);
    float*   lstats = (float*)alloc(LSTATS_WORDS * 4);        // bnpart + gmax + gsum
    float*   bnss   = (float*)alloc(64 * 4);
    int*     csrsrc = (int*)alloc(EE * 4);
    uint4*   ecsrh  = (uint4*)alloc((size_t)EE * 16);         // fp16 edge attrs

    const int* srcA = eidx;
    const int* dstA = eidx + EE;

    // --- graph prep (once per call) ---
    (void)hipMemsetAsync(degcnt, 0, 2 * NN * 4, stream);

    deg_kernel<<<(EE + 255) / 256, 256, 0, stream>>>(dstA, deg);
    scan1_kernel<<<98, 256, 0, stream>>>(deg, rowp, blks);
    scan2_kernel<<<1, 128, 0, stream>>>(blks, 98, bidx, gstart);
    scan3_kernel<<<98, 256, 0, stream>>>(rowp, blks);
    fill_kernel<<<(EE + 255) / 256, 256, 0, stream>>>(dstA, rowp, cnt2, csre);
    sortseg_kernel<<<98, 256, 0, stream>>>(rowp, csre);
    csr_gather_kernel<<<(EE + 255) / 256, 256, 0, stream>>>(csre, srcA, eattr, csrsrc, ecsrh);

    const float* hin = x;
    for (int l = 0; l < LL; ++l) {
        qkvs_kernel<<<782, 256, 0, stream>>>(
            (l == 0) ? x : hlin, (l > 0) ? 1 : 0, bnss,
            Wq + l * FF * HCC, bq + l * HCC,
            Wk + l * FF * HCC, bk + l * HCC,
            Wv + l * FF * HCC, bv + l * HCC,
            Wskip + l * FF * HCC, bskip + l * HCC,
            qH, kvB, skH, lstats);

        attn_kernel<<<(NN + 3) / 4, 256, 0, stream>>>(
            (const uint2*)qH, (const uint4*)kvB, (const uint2*)skH,
            ecsrh, csrsrc, rowp, bidx,
            We + l * EDD * HCC, be + l * HCC,
            Wbeta + l * 3 * HCC,
            Wlin + l * HCC * FF, blin + l * FF,
            hlin, lstats,
            (l > 0) ? 1 : 0, (l < LL - 1) ? 1 : 0);

        bnfin_kernel<<<1, 32, 0, stream>>>(lstats, bng + l * FF, bnb + l * FF, bnss);

        if (l > 0) {
            repupd_kernel<<<8, 256, 0, stream>>>(lstats, bnss, gstart, rep, (l == 1) ? 1 : 0);
        }
        hin = hlin;
    }

    readout_kernel<<<64, 128, 0, stream>>>(rep, W1, b1, W2, b2, W3, b3, out);
}